// Round 2
// baseline (442.904 us; speedup 1.0000x reference)
//
#include <hip/hip_runtime.h>
#include <math.h>

// Problem constants
#define BN   128    // batch
#define LN   2048   // encoder length
#define HN   256    // hidden
#define EN   256    // embed
#define CHUNKS 8
#define PSTRIDE 260   // per-(b,chunk) partial: ctx[256], m, s, pad

__device__ __forceinline__ float sigmoidf_(float x) { return 1.0f / (1.0f + __expf(-x)); }
__device__ __forceinline__ float tanhf_(float x)    { return 1.0f - 2.0f / (__expf(2.0f * x) + 1.0f); }

// ---------------------------------------------------------------------------
// K1: one pass over encoder_outputs with online softmax, 8-row batches.
// grid (CHUNKS, BN), block 256 (4 waves). Wave w handles 64 consecutive rows
// in 8 batches of 8: 8 loads in flight, 48 independent (pipelined) shuffles
// per batch, ONE serial online-softmax update per 8 rows.
// ---------------------------------------------------------------------------
__global__ __launch_bounds__(256) void attn_partial(
    const float* __restrict__ enc,      // [B][L][H]
    const float* __restrict__ hidden1,  // [B][H]
    float* __restrict__ partials)       // [B][CHUNKS][PSTRIDE]
{
    const int chunk = blockIdx.x;
    const int b     = blockIdx.y;
    const int t     = threadIdx.x;
    const int wave  = t >> 6;
    const int lane  = t & 63;

    __shared__ float lds_ctx[4][256];
    __shared__ float lds_m[4], lds_s[4];

    const float4 h4 = *(const float4*)(hidden1 + b * HN + lane * 4);

    float  m = -INFINITY, s = 0.0f;
    float4 ctx = make_float4(0.f, 0.f, 0.f, 0.f);

    const float* rowp = enc + ((size_t)b * LN + (size_t)chunk * 256 + wave * 64) * HN + lane * 4;

    for (int batch = 0; batch < 8; ++batch) {
        float4 e[8];
        float  d[8];
        #pragma unroll
        for (int r = 0; r < 8; ++r) {
            e[r] = *(const float4*)(rowp + r * HN);
            d[r] = e[r].x * h4.x + e[r].y * h4.y + e[r].z * h4.z + e[r].w * h4.w;
        }
        rowp += 8 * HN;
        #pragma unroll
        for (int off = 1; off < 64; off <<= 1) {
            #pragma unroll
            for (int r = 0; r < 8; ++r) d[r] += __shfl_xor(d[r], off, 64);
        }
        float dmax = d[0];
        #pragma unroll
        for (int r = 1; r < 8; ++r) dmax = fmaxf(dmax, d[r]);
        float mn   = fmaxf(m, dmax);
        float corr = __expf(m - mn);        // exp(-inf)=0 on first batch
        float psum = 0.0f;
        float4 add = make_float4(0.f, 0.f, 0.f, 0.f);
        #pragma unroll
        for (int r = 0; r < 8; ++r) {
            float p = __expf(d[r] - mn);
            psum  += p;
            add.x += p * e[r].x; add.y += p * e[r].y;
            add.z += p * e[r].z; add.w += p * e[r].w;
        }
        s = s * corr + psum;
        ctx.x = ctx.x * corr + add.x;
        ctx.y = ctx.y * corr + add.y;
        ctx.z = ctx.z * corr + add.z;
        ctx.w = ctx.w * corr + add.w;
        m = mn;
    }

    *(float4*)&lds_ctx[wave][lane * 4] = ctx;
    if (lane == 0) { lds_m[wave] = m; lds_s[wave] = s; }
    __syncthreads();

    // combine the 4 waves; thread t == h-index j
    float M = fmaxf(fmaxf(lds_m[0], lds_m[1]), fmaxf(lds_m[2], lds_m[3]));
    float e0 = __expf(lds_m[0] - M), e1 = __expf(lds_m[1] - M);
    float e2 = __expf(lds_m[2] - M), e3 = __expf(lds_m[3] - M);
    float cj = e0 * lds_ctx[0][t] + e1 * lds_ctx[1][t] + e2 * lds_ctx[2][t] + e3 * lds_ctx[3][t];
    float S  = e0 * lds_s[0] + e1 * lds_s[1] + e2 * lds_s[2] + e3 * lds_s[3];

    float* pb = partials + ((size_t)b * CHUNKS + chunk) * PSTRIDE;
    pb[t] = cj;
    if (t == 0) { pb[256] = M; pb[257] = S; }
}

// ---------------------------------------------------------------------------
// K2: merge chunk partials -> context; build xh1 = [ctx | h1_prev] (K=512)
// and xh2 = [embed | (h1 later) | h2_prev] (K=768). grid 128, block 256.
// ---------------------------------------------------------------------------
__global__ __launch_bounds__(256) void combine_prep(
    const float* __restrict__ partials,
    const float* __restrict__ hidden1,
    const float* __restrict__ embed,
    const float* __restrict__ hidden2,
    float* __restrict__ xh1,    // [B][512]
    float* __restrict__ xh2)    // [B][768]
{
    const int b = blockIdx.x;
    const int j = threadIdx.x;
    const float* pb = partials + (size_t)b * CHUNKS * PSTRIDE;

    float mk[CHUNKS], sk[CHUNKS];
    float M = -INFINITY;
    #pragma unroll
    for (int k = 0; k < CHUNKS; ++k) {
        mk[k] = pb[k * PSTRIDE + 256];
        sk[k] = pb[k * PSTRIDE + 257];
        M = fmaxf(M, mk[k]);
    }
    float S = 0.0f, cj = 0.0f;
    #pragma unroll
    for (int k = 0; k < CHUNKS; ++k) {
        float e = __expf(mk[k] - M);
        S  += e * sk[k];
        cj += e * pb[k * PSTRIDE + j];
    }
    cj /= S;

    xh1[b * 512 + j]       = cj;
    xh1[b * 512 + 256 + j] = hidden1[b * HN + j];
    xh2[b * 768 + j]       = embed[b * EN + j];
    xh2[b * 768 + 512 + j] = hidden2[b * HN + j];
}

// ---------------------------------------------------------------------------
// K3: LSTM1, K=512. grid (32 jb, 4 bb), block 128 = 8 jl x 16 bl, 2 b/thread.
// LDS wq: 32 gate rows (q*8+jl) x 512 k, row-major with per-row float4
// rotation swizzle (col' = (col + row) & 127):
//   - staging writes: contiguous ds_write_b128, conflict-free
//   - compute reads: distinct bank-quads across jl, bl-broadcast, conflict-free
// ---------------------------------------------------------------------------
__global__ __launch_bounds__(128) void lstm1_kernel(
    const float* __restrict__ xh,     // [B][512]
    const float* __restrict__ w_ih,   // [1024][256]
    const float* __restrict__ w_hh,   // [1024][256]
    const float* __restrict__ b_ih,
    const float* __restrict__ b_hh,
    const float* __restrict__ cell,   // [B][256]
    float* __restrict__ h_out,
    float* __restrict__ c_out,
    float* __restrict__ xh2)          // writes [b][256+j]
{
    __shared__ float wq[32 * 512];    // 64 KiB
    const int t  = threadIdx.x;
    const int jb = blockIdx.x;        // 0..31
    const int bb = blockIdx.y;        // 0..3

    // stage 32 gate rows; one row (512 floats = 128 float4) per iteration
    #pragma unroll 16
    for (int row = 0; row < 32; ++row) {
        int q  = row >> 3, jl = row & 7;
        int g  = q * 256 + jb * 8 + jl;
        int k  = t * 4;
        float4 v = (k < 256) ? *(const float4*)(w_ih + (size_t)g * 256 + k)
                             : *(const float4*)(w_hh + (size_t)g * 256 + (k - 256));
        int cp = (t + row) & 127;
        *(float4*)&wq[row * 512 + cp * 4] = v;
    }
    __syncthreads();

    const int jl = t & 7, bl = t >> 3;
    const int b0 = bb * 32 + bl, b1 = b0 + 16;
    const int j  = jb * 8 + jl;

    float accA[4] = {0.f, 0.f, 0.f, 0.f};
    float accB[4] = {0.f, 0.f, 0.f, 0.f};
    const float* xra = xh + (size_t)b0 * 512;
    const float* xrb = xh + (size_t)b1 * 512;

    #pragma unroll 8
    for (int k4 = 0; k4 < 128; ++k4) {
        float4 xa = *(const float4*)(xra + k4 * 4);
        float4 xb = *(const float4*)(xrb + k4 * 4);
        #pragma unroll
        for (int q = 0; q < 4; ++q) {
            int row = q * 8 + jl;
            float4 w4 = *(float4*)&wq[row * 512 + ((k4 + row) & 127) * 4];
            accA[q] += w4.x * xa.x + w4.y * xa.y + w4.z * xa.z + w4.w * xa.w;
            accB[q] += w4.x * xb.x + w4.y * xb.y + w4.z * xb.z + w4.w * xb.w;
        }
    }

    float bias[4];
    #pragma unroll
    for (int q = 0; q < 4; ++q) bias[q] = b_ih[q * 256 + j] + b_hh[q * 256 + j];

    {
        float gi = accA[0] + bias[0], gf = accA[1] + bias[1];
        float gg = accA[2] + bias[2], go = accA[3] + bias[3];
        float cp = cell[b0 * HN + j];
        float cn = sigmoidf_(gf) * cp + sigmoidf_(gi) * tanhf_(gg);
        float hn = sigmoidf_(go) * tanhf_(cn);
        c_out[b0 * HN + j] = cn;
        h_out[b0 * HN + j] = hn;
        xh2[b0 * 768 + 256 + j] = hn;
    }
    {
        float gi = accB[0] + bias[0], gf = accB[1] + bias[1];
        float gg = accB[2] + bias[2], go = accB[3] + bias[3];
        float cp = cell[b1 * HN + j];
        float cn = sigmoidf_(gf) * cp + sigmoidf_(gi) * tanhf_(gg);
        float hn = sigmoidf_(go) * tanhf_(cn);
        c_out[b1 * HN + j] = cn;
        h_out[b1 * HN + j] = hn;
        xh2[b1 * 768 + 256 + j] = hn;
    }
}

// ---------------------------------------------------------------------------
// K4: LSTM2, K=768. grid (64 jb, 2 bb), block 128 = 4 jl x 32 bl, 2 b/thread.
// LDS: wA = 16 rows x 512 (w_ih2 part, rotate &127), wB = 16 rows x 256
// (w_hh2 part, rotate &63). 48 KiB total.
// ---------------------------------------------------------------------------
__global__ __launch_bounds__(128) void lstm2_kernel(
    const float* __restrict__ xh,     // [B][768] = [embed | h1 | h2_prev]
    const float* __restrict__ w_ih,   // [1024][512]
    const float* __restrict__ w_hh,   // [1024][256]
    const float* __restrict__ b_ih,
    const float* __restrict__ b_hh,
    const float* __restrict__ cell,   // [B][256]
    float* __restrict__ out0,         // d_out chunk 0 (outputs == h2)
    float* __restrict__ h_out,        // d_out chunk 3
    float* __restrict__ c_out)        // d_out chunk 4
{
    __shared__ float wA[16 * 512];    // 32 KiB
    __shared__ float wB[16 * 256];    // 16 KiB
    const int t  = threadIdx.x;
    const int jb = blockIdx.x;        // 0..63
    const int bb = blockIdx.y;        // 0..1

    // stage wA: 16 rows x 512 floats, one row per iteration
    #pragma unroll 16
    for (int row = 0; row < 16; ++row) {
        int q  = row >> 2, jl = row & 3;
        int g  = q * 256 + jb * 4 + jl;
        float4 v = *(const float4*)(w_ih + (size_t)g * 512 + t * 4);
        int cp = (t + row) & 127;
        *(float4*)&wA[row * 512 + cp * 4] = v;
    }
    // stage wB: 16 rows x 256 floats, two rows per iteration
    #pragma unroll 8
    for (int it = 0; it < 8; ++it) {
        int row = it * 2 + (t >> 6);
        int c   = t & 63;
        int q   = row >> 2, jl = row & 3;
        int g   = q * 256 + jb * 4 + jl;
        float4 v = *(const float4*)(w_hh + (size_t)g * 256 + c * 4);
        int cp = (c + row) & 63;
        *(float4*)&wB[row * 256 + cp * 4] = v;
    }
    __syncthreads();

    const int jl = t & 3, bl = t >> 2;
    const int b0 = bb * 64 + bl, b1 = b0 + 32;
    const int j  = jb * 4 + jl;

    float accA[4] = {0.f, 0.f, 0.f, 0.f};
    float accB[4] = {0.f, 0.f, 0.f, 0.f};
    const float* xra = xh + (size_t)b0 * 768;
    const float* xrb = xh + (size_t)b1 * 768;

    #pragma unroll 8
    for (int k4 = 0; k4 < 128; ++k4) {       // w_ih2 part (K 0..511)
        float4 xa = *(const float4*)(xra + k4 * 4);
        float4 xb = *(const float4*)(xrb + k4 * 4);
        #pragma unroll
        for (int q = 0; q < 4; ++q) {
            int row = q * 4 + jl;
            float4 w4 = *(float4*)&wA[row * 512 + ((k4 + row) & 127) * 4];
            accA[q] += w4.x * xa.x + w4.y * xa.y + w4.z * xa.z + w4.w * xa.w;
            accB[q] += w4.x * xb.x + w4.y * xb.y + w4.z * xb.z + w4.w * xb.w;
        }
    }
    #pragma unroll 8
    for (int k4 = 0; k4 < 64; ++k4) {        // w_hh2 part (K 512..767)
        float4 xa = *(const float4*)(xra + 512 + k4 * 4);
        float4 xb = *(const float4*)(xrb + 512 + k4 * 4);
        #pragma unroll
        for (int q = 0; q < 4; ++q) {
            int row = q * 4 + jl;
            float4 w4 = *(float4*)&wB[row * 256 + ((k4 + row) & 63) * 4];
            accA[q] += w4.x * xa.x + w4.y * xa.y + w4.z * xa.z + w4.w * xa.w;
            accB[q] += w4.x * xb.x + w4.y * xb.y + w4.z * xb.z + w4.w * xb.w;
        }
    }

    float bias[4];
    #pragma unroll
    for (int q = 0; q < 4; ++q) bias[q] = b_ih[q * 256 + j] + b_hh[q * 256 + j];

    {
        float gi = accA[0] + bias[0], gf = accA[1] + bias[1];
        float gg = accA[2] + bias[2], go = accA[3] + bias[3];
        float cp = cell[b0 * HN + j];
        float cn = sigmoidf_(gf) * cp + sigmoidf_(gi) * tanhf_(gg);
        float hn = sigmoidf_(go) * tanhf_(cn);
        out0[b0 * HN + j] = hn; h_out[b0 * HN + j] = hn; c_out[b0 * HN + j] = cn;
    }
    {
        float gi = accB[0] + bias[0], gf = accB[1] + bias[1];
        float gg = accB[2] + bias[2], go = accB[3] + bias[3];
        float cp = cell[b1 * HN + j];
        float cn = sigmoidf_(gf) * cp + sigmoidf_(gi) * tanhf_(gg);
        float hn = sigmoidf_(go) * tanhf_(cn);
        out0[b1 * HN + j] = hn; h_out[b1 * HN + j] = hn; c_out[b1 * HN + j] = cn;
    }
}

// ---------------------------------------------------------------------------
extern "C" void kernel_launch(void* const* d_in, const int* in_sizes, int n_in,
                              void* d_out, int out_size, void* d_ws, size_t ws_size,
                              hipStream_t stream)
{
    const float* embed   = (const float*)d_in[0];   // (B,1,E)
    const float* enc     = (const float*)d_in[1];   // (B,L,H)
    const float* hidden1 = (const float*)d_in[2];   // (1,B,H)
    const float* cell1   = (const float*)d_in[3];
    const float* hidden2 = (const float*)d_in[4];
    const float* cell2   = (const float*)d_in[5];
    const float* w_ih1   = (const float*)d_in[6];   // (1024,256)
    const float* w_hh1   = (const float*)d_in[7];   // (1024,256)
    const float* b_ih1   = (const float*)d_in[8];
    const float* b_hh1   = (const float*)d_in[9];
    const float* w_ih2   = (const float*)d_in[10];  // (1024,512)
    const float* w_hh2   = (const float*)d_in[11];  // (1024,256)
    const float* b_ih2   = (const float*)d_in[12];
    const float* b_hh2   = (const float*)d_in[13];

    float* out = (float*)d_out;
    // out layout: [0) outputs(h2) 32768 | 32768) h1 | 65536) c1 | 98304) h2 | 131072) c2
    float* ws = (float*)d_ws;
    float* partials = ws;                                  // 128*8*260 floats
    float* xh1 = ws + (size_t)BN * CHUNKS * PSTRIDE;       // 128*512
    float* xh2 = xh1 + (size_t)BN * 512;                   // 128*768

    attn_partial<<<dim3(CHUNKS, BN), 256, 0, stream>>>(enc, hidden1, partials);
    combine_prep<<<dim3(BN), 256, 0, stream>>>(partials, hidden1, embed, hidden2, xh1, xh2);
    lstm1_kernel<<<dim3(32, 4), 128, 0, stream>>>(xh1, w_ih1, w_hh1, b_ih1, b_hh1, cell1,
                                                  out + 32768, out + 65536, xh2);
    lstm2_kernel<<<dim3(64, 2), 128, 0, stream>>>(xh2, w_ih2, w_hh2, b_ih2, b_hh2, cell2,
                                                  out, out + 98304, out + 131072);
}

// Round 3
// 441.124 us; speedup vs baseline: 1.0040x; 1.0040x over previous
//
#include <hip/hip_runtime.h>
#include <math.h>

// Problem constants
#define BN   128    // batch
#define LN   2048   // encoder length
#define HN   256    // hidden
#define EN   256    // embed
#define CHUNKS 16
#define ROWS_PER_CHUNK (LN / CHUNKS)   // 128 rows: 32 per wave = 4 batches of 8
#define PSTRIDE 260   // per-(b,chunk) partial: ctx[256], m, s, pad

__device__ __forceinline__ float sigmoidf_(float x) { return 1.0f / (1.0f + __expf(-x)); }
__device__ __forceinline__ float tanhf_(float x)    { return 1.0f - 2.0f / (__expf(2.0f * x) + 1.0f); }

// ---------------------------------------------------------------------------
// K1: one pass over encoder_outputs with online softmax, 8-row batches.
// grid (CHUNKS, BN), block 256 (4 waves) -> 2048 blocks = 8/CU = 32 waves/CU.
// Wave handles 32 consecutive rows in 4 batches of 8: 8 loads in flight,
// 48 pipelined shuffles per batch, ONE serial softmax update per 8 rows.
// ---------------------------------------------------------------------------
__global__ __launch_bounds__(256) void attn_partial(
    const float* __restrict__ enc,      // [B][L][H]
    const float* __restrict__ hidden1,  // [B][H]
    float* __restrict__ partials)       // [B][CHUNKS][PSTRIDE]
{
    const int chunk = blockIdx.x;
    const int b     = blockIdx.y;
    const int t     = threadIdx.x;
    const int wave  = t >> 6;
    const int lane  = t & 63;

    __shared__ float lds_ctx[4][256];
    __shared__ float lds_m[4], lds_s[4];

    const float4 h4 = *(const float4*)(hidden1 + b * HN + lane * 4);

    float  m = -INFINITY, s = 0.0f;
    float4 ctx = make_float4(0.f, 0.f, 0.f, 0.f);

    const float* rowp = enc + ((size_t)b * LN + (size_t)chunk * ROWS_PER_CHUNK + wave * 32) * HN + lane * 4;

    for (int batch = 0; batch < 4; ++batch) {
        float4 e[8];
        float  d[8];
        #pragma unroll
        for (int r = 0; r < 8; ++r) {
            e[r] = *(const float4*)(rowp + r * HN);
            d[r] = e[r].x * h4.x + e[r].y * h4.y + e[r].z * h4.z + e[r].w * h4.w;
        }
        rowp += 8 * HN;
        #pragma unroll
        for (int off = 1; off < 64; off <<= 1) {
            #pragma unroll
            for (int r = 0; r < 8; ++r) d[r] += __shfl_xor(d[r], off, 64);
        }
        float dmax = d[0];
        #pragma unroll
        for (int r = 1; r < 8; ++r) dmax = fmaxf(dmax, d[r]);
        float mn   = fmaxf(m, dmax);
        float corr = __expf(m - mn);        // exp(-inf)=0 on first batch
        float psum = 0.0f;
        float4 add = make_float4(0.f, 0.f, 0.f, 0.f);
        #pragma unroll
        for (int r = 0; r < 8; ++r) {
            float p = __expf(d[r] - mn);
            psum  += p;
            add.x += p * e[r].x; add.y += p * e[r].y;
            add.z += p * e[r].z; add.w += p * e[r].w;
        }
        s = s * corr + psum;
        ctx.x = ctx.x * corr + add.x;
        ctx.y = ctx.y * corr + add.y;
        ctx.z = ctx.z * corr + add.z;
        ctx.w = ctx.w * corr + add.w;
        m = mn;
    }

    *(float4*)&lds_ctx[wave][lane * 4] = ctx;
    if (lane == 0) { lds_m[wave] = m; lds_s[wave] = s; }
    __syncthreads();

    // combine the 4 waves; thread t == h-index j
    float M = fmaxf(fmaxf(lds_m[0], lds_m[1]), fmaxf(lds_m[2], lds_m[3]));
    float e0 = __expf(lds_m[0] - M), e1 = __expf(lds_m[1] - M);
    float e2 = __expf(lds_m[2] - M), e3 = __expf(lds_m[3] - M);
    float cj = e0 * lds_ctx[0][t] + e1 * lds_ctx[1][t] + e2 * lds_ctx[2][t] + e3 * lds_ctx[3][t];
    float S  = e0 * lds_s[0] + e1 * lds_s[1] + e2 * lds_s[2] + e3 * lds_s[3];

    float* pb = partials + ((size_t)b * CHUNKS + chunk) * PSTRIDE;
    pb[t] = cj;
    if (t == 0) { pb[256] = M; pb[257] = S; }
}

// ---------------------------------------------------------------------------
// K2: merge chunk partials -> normalized context ONLY (128 KB write).
// grid 128, block 256 (thread == j).
// ---------------------------------------------------------------------------
__global__ __launch_bounds__(256) void combine_ctx(
    const float* __restrict__ partials,
    float* __restrict__ ctx)    // [B][256]
{
    const int b = blockIdx.x;
    const int j = threadIdx.x;
    const float* pb = partials + (size_t)b * CHUNKS * PSTRIDE;

    float mk[CHUNKS], sk[CHUNKS];
    float M = -INFINITY;
    #pragma unroll
    for (int k = 0; k < CHUNKS; ++k) {
        mk[k] = pb[k * PSTRIDE + 256];
        sk[k] = pb[k * PSTRIDE + 257];
        M = fmaxf(M, mk[k]);
    }
    float S = 0.0f, cj = 0.0f;
    #pragma unroll
    for (int k = 0; k < CHUNKS; ++k) {
        float e = __expf(mk[k] - M);
        S  += e * sk[k];
        cj += e * pb[k * PSTRIDE + j];
    }
    ctx[b * HN + j] = cj / S;
}

// ---------------------------------------------------------------------------
// K3: LSTM1, K=512 = [ctx | hidden1]. grid (32 jb, 4 bb), block 128 =
// 8 jl x 16 bl, 2 batches/thread. LDS wq: 32 gate rows x 512 k, row-major
// with per-row float4 rotation swizzle -> conflict-free writes AND reads.
// ---------------------------------------------------------------------------
__global__ __launch_bounds__(128) void lstm1_kernel(
    const float* __restrict__ ctx,    // [B][256]
    const float* __restrict__ hidden1,// [B][256]
    const float* __restrict__ w_ih,   // [1024][256]
    const float* __restrict__ w_hh,   // [1024][256]
    const float* __restrict__ b_ih,
    const float* __restrict__ b_hh,
    const float* __restrict__ cell,   // [B][256]
    float* __restrict__ h_out,
    float* __restrict__ c_out)
{
    __shared__ float wq[32 * 512];    // 64 KiB
    const int t  = threadIdx.x;
    const int jb = blockIdx.x;        // 0..31
    const int bb = blockIdx.y;        // 0..3

    #pragma unroll 16
    for (int row = 0; row < 32; ++row) {
        int q  = row >> 3, jl = row & 7;
        int g  = q * 256 + jb * 8 + jl;
        int k  = t * 4;
        float4 v = (k < 256) ? *(const float4*)(w_ih + (size_t)g * 256 + k)
                             : *(const float4*)(w_hh + (size_t)g * 256 + (k - 256));
        int cp = (t + row) & 127;
        *(float4*)&wq[row * 512 + cp * 4] = v;
    }
    __syncthreads();

    const int jl = t & 7, bl = t >> 3;
    const int b0 = bb * 32 + bl, b1 = b0 + 16;
    const int j  = jb * 8 + jl;

    float accA[4] = {0.f, 0.f, 0.f, 0.f};
    float accB[4] = {0.f, 0.f, 0.f, 0.f};
    const float* xa0 = ctx     + (size_t)b0 * HN;
    const float* xb0 = ctx     + (size_t)b1 * HN;
    const float* xa1 = hidden1 + (size_t)b0 * HN;
    const float* xb1 = hidden1 + (size_t)b1 * HN;

    #pragma unroll 8
    for (int k4 = 0; k4 < 64; ++k4) {        // ctx half (k 0..255)
        float4 xa = *(const float4*)(xa0 + k4 * 4);
        float4 xb = *(const float4*)(xb0 + k4 * 4);
        #pragma unroll
        for (int q = 0; q < 4; ++q) {
            int row = q * 8 + jl;
            float4 w4 = *(float4*)&wq[row * 512 + ((k4 + row) & 127) * 4];
            accA[q] += w4.x * xa.x + w4.y * xa.y + w4.z * xa.z + w4.w * xa.w;
            accB[q] += w4.x * xb.x + w4.y * xb.y + w4.z * xb.z + w4.w * xb.w;
        }
    }
    #pragma unroll 8
    for (int k4 = 64; k4 < 128; ++k4) {      // hidden1 half (k 256..511)
        float4 xa = *(const float4*)(xa1 + (k4 - 64) * 4);
        float4 xb = *(const float4*)(xb1 + (k4 - 64) * 4);
        #pragma unroll
        for (int q = 0; q < 4; ++q) {
            int row = q * 8 + jl;
            float4 w4 = *(float4*)&wq[row * 512 + ((k4 + row) & 127) * 4];
            accA[q] += w4.x * xa.x + w4.y * xa.y + w4.z * xa.z + w4.w * xa.w;
            accB[q] += w4.x * xb.x + w4.y * xb.y + w4.z * xb.z + w4.w * xb.w;
        }
    }

    float bias[4];
    #pragma unroll
    for (int q = 0; q < 4; ++q) bias[q] = b_ih[q * 256 + j] + b_hh[q * 256 + j];

    {
        float gi = accA[0] + bias[0], gf = accA[1] + bias[1];
        float gg = accA[2] + bias[2], go = accA[3] + bias[3];
        float cp = cell[b0 * HN + j];
        float cn = sigmoidf_(gf) * cp + sigmoidf_(gi) * tanhf_(gg);
        float hn = sigmoidf_(go) * tanhf_(cn);
        c_out[b0 * HN + j] = cn;
        h_out[b0 * HN + j] = hn;
    }
    {
        float gi = accB[0] + bias[0], gf = accB[1] + bias[1];
        float gg = accB[2] + bias[2], go = accB[3] + bias[3];
        float cp = cell[b1 * HN + j];
        float cn = sigmoidf_(gf) * cp + sigmoidf_(gi) * tanhf_(gg);
        float hn = sigmoidf_(go) * tanhf_(cn);
        c_out[b1 * HN + j] = cn;
        h_out[b1 * HN + j] = hn;
    }
}

// ---------------------------------------------------------------------------
// K4: LSTM2, K=768 = [embed | h1 | h2_prev], read directly from the three
// sources (no xh2 buffer). grid (64 jb, 2 bb), block 128 = 4 jl x 32 bl,
// 2 batches/thread. LDS: wA 16x512 (w_ih2, rotate &127), wB 16x256 (w_hh2,
// rotate &63). 48 KiB.
// ---------------------------------------------------------------------------
__global__ __launch_bounds__(128) void lstm2_kernel(
    const float* __restrict__ embed,  // [B][256]
    const float* __restrict__ h1,     // [B][256] (just written by lstm1)
    const float* __restrict__ h2p,    // [B][256]
    const float* __restrict__ w_ih,   // [1024][512]
    const float* __restrict__ w_hh,   // [1024][256]
    const float* __restrict__ b_ih,
    const float* __restrict__ b_hh,
    const float* __restrict__ cell,   // [B][256]
    float* __restrict__ out0,         // outputs chunk (== h2)
    float* __restrict__ h_out,        // h2 chunk
    float* __restrict__ c_out)        // c2 chunk
{
    __shared__ float wA[16 * 512];    // 32 KiB
    __shared__ float wB[16 * 256];    // 16 KiB
    const int t  = threadIdx.x;
    const int jb = blockIdx.x;        // 0..63
    const int bb = blockIdx.y;        // 0..1

    #pragma unroll 16
    for (int row = 0; row < 16; ++row) {
        int q  = row >> 2, jl = row & 3;
        int g  = q * 256 + jb * 4 + jl;
        float4 v = *(const float4*)(w_ih + (size_t)g * 512 + t * 4);
        int cp = (t + row) & 127;
        *(float4*)&wA[row * 512 + cp * 4] = v;
    }
    #pragma unroll 8
    for (int it = 0; it < 8; ++it) {
        int row = it * 2 + (t >> 6);
        int c   = t & 63;
        int q   = row >> 2, jl = row & 3;
        int g   = q * 256 + jb * 4 + jl;
        float4 v = *(const float4*)(w_hh + (size_t)g * 256 + c * 4);
        int cp = (c + row) & 63;
        *(float4*)&wB[row * 256 + cp * 4] = v;
    }
    __syncthreads();

    const int jl = t & 3, bl = t >> 2;
    const int b0 = bb * 64 + bl, b1 = b0 + 32;
    const int j  = jb * 4 + jl;

    float accA[4] = {0.f, 0.f, 0.f, 0.f};
    float accB[4] = {0.f, 0.f, 0.f, 0.f};

    #pragma unroll 8
    for (int k4 = 0; k4 < 64; ++k4) {        // embed span (k 0..255)
        float4 xa = *(const float4*)(embed + (size_t)b0 * HN + k4 * 4);
        float4 xb = *(const float4*)(embed + (size_t)b1 * HN + k4 * 4);
        #pragma unroll
        for (int q = 0; q < 4; ++q) {
            int row = q * 4 + jl;
            float4 w4 = *(float4*)&wA[row * 512 + ((k4 + row) & 127) * 4];
            accA[q] += w4.x * xa.x + w4.y * xa.y + w4.z * xa.z + w4.w * xa.w;
            accB[q] += w4.x * xb.x + w4.y * xb.y + w4.z * xb.z + w4.w * xb.w;
        }
    }
    #pragma unroll 8
    for (int k4 = 64; k4 < 128; ++k4) {      // h1 span (k 256..511)
        float4 xa = *(const float4*)(h1 + (size_t)b0 * HN + (k4 - 64) * 4);
        float4 xb = *(const float4*)(h1 + (size_t)b1 * HN + (k4 - 64) * 4);
        #pragma unroll
        for (int q = 0; q < 4; ++q) {
            int row = q * 4 + jl;
            float4 w4 = *(float4*)&wA[row * 512 + ((k4 + row) & 127) * 4];
            accA[q] += w4.x * xa.x + w4.y * xa.y + w4.z * xa.z + w4.w * xa.w;
            accB[q] += w4.x * xb.x + w4.y * xb.y + w4.z * xb.z + w4.w * xb.w;
        }
    }
    #pragma unroll 8
    for (int k4 = 0; k4 < 64; ++k4) {        // h2_prev span (k 512..767)
        float4 xa = *(const float4*)(h2p + (size_t)b0 * HN + k4 * 4);
        float4 xb = *(const float4*)(h2p + (size_t)b1 * HN + k4 * 4);
        #pragma unroll
        for (int q = 0; q < 4; ++q) {
            int row = q * 4 + jl;
            float4 w4 = *(float4*)&wB[row * 256 + ((k4 + row) & 63) * 4];
            accA[q] += w4.x * xa.x + w4.y * xa.y + w4.z * xa.z + w4.w * xa.w;
            accB[q] += w4.x * xb.x + w4.y * xb.y + w4.z * xb.z + w4.w * xb.w;
        }
    }

    float bias[4];
    #pragma unroll
    for (int q = 0; q < 4; ++q) bias[q] = b_ih[q * 256 + j] + b_hh[q * 256 + j];

    {
        float gi = accA[0] + bias[0], gf = accA[1] + bias[1];
        float gg = accA[2] + bias[2], go = accA[3] + bias[3];
        float cp = cell[b0 * HN + j];
        float cn = sigmoidf_(gf) * cp + sigmoidf_(gi) * tanhf_(gg);
        float hn = sigmoidf_(go) * tanhf_(cn);
        out0[b0 * HN + j] = hn; h_out[b0 * HN + j] = hn; c_out[b0 * HN + j] = cn;
    }
    {
        float gi = accB[0] + bias[0], gf = accB[1] + bias[1];
        float gg = accB[2] + bias[2], go = accB[3] + bias[3];
        float cp = cell[b1 * HN + j];
        float cn = sigmoidf_(gf) * cp + sigmoidf_(gi) * tanhf_(gg);
        float hn = sigmoidf_(go) * tanhf_(cn);
        out0[b1 * HN + j] = hn; h_out[b1 * HN + j] = hn; c_out[b1 * HN + j] = cn;
    }
}

// ---------------------------------------------------------------------------
extern "C" void kernel_launch(void* const* d_in, const int* in_sizes, int n_in,
                              void* d_out, int out_size, void* d_ws, size_t ws_size,
                              hipStream_t stream)
{
    const float* embed   = (const float*)d_in[0];   // (B,1,E)
    const float* enc     = (const float*)d_in[1];   // (B,L,H)
    const float* hidden1 = (const float*)d_in[2];   // (1,B,H)
    const float* cell1   = (const float*)d_in[3];
    const float* hidden2 = (const float*)d_in[4];
    const float* cell2   = (const float*)d_in[5];
    const float* w_ih1   = (const float*)d_in[6];   // (1024,256)
    const float* w_hh1   = (const float*)d_in[7];   // (1024,256)
    const float* b_ih1   = (const float*)d_in[8];
    const float* b_hh1   = (const float*)d_in[9];
    const float* w_ih2   = (const float*)d_in[10];  // (1024,512)
    const float* w_hh2   = (const float*)d_in[11];  // (1024,256)
    const float* b_ih2   = (const float*)d_in[12];
    const float* b_hh2   = (const float*)d_in[13];

    float* out = (float*)d_out;
    // out layout: [0) outputs(h2) 32768 | 32768) h1 | 65536) c1 | 98304) h2 | 131072) c2
    float* ws = (float*)d_ws;
    float* partials = ws;                                  // 128*16*260 floats
    float* ctx = ws + (size_t)BN * CHUNKS * PSTRIDE;       // 128*256

    attn_partial<<<dim3(CHUNKS, BN), 256, 0, stream>>>(enc, hidden1, partials);
    combine_ctx<<<dim3(BN), 256, 0, stream>>>(partials, ctx);
    lstm1_kernel<<<dim3(32, 4), 128, 0, stream>>>(ctx, hidden1, w_ih1, w_hh1, b_ih1, b_hh1,
                                                  cell1, out + 32768, out + 65536);
    lstm2_kernel<<<dim3(64, 2), 128, 0, stream>>>(embed, out + 32768, hidden2,
                                                  w_ih2, w_hh2, b_ih2, b_hh2, cell2,
                                                  out, out + 98304, out + 131072);
}